// Round 1
// baseline (3096.014 us; speedup 1.0000x reference)
//
#include <hip/hip_runtime.h>

#define N_NODES   100000
#define N_EDGES   1600000
#define COLS      64      // 10 one-hot + 54 mlp
#define HID       128
#define OUT2      54
#define W2_PAD    56      // pad LDS rows to 16B alignment

// ---------------- Pass 1: compute w, write to out, atomic segment-sum ----------------
// Each block: 256 threads, 512 edges (2 per thread). 1.6M / 512 = 3125 blocks exactly.
__global__ __launch_bounds__(256) void pass1_kernel(
    const float* __restrict__ edge_attr,   // (E,1)
    const int*   __restrict__ edge_index,  // (2,E) int32; row 0 = src
    const float* __restrict__ W1,          // (1,128)
    const float* __restrict__ b1,          // (128,)
    const float* __restrict__ W2,          // (128,54)
    const float* __restrict__ b2,          // (54,)
    float* __restrict__ wout,              // (E,64)  -> d_out
    float* __restrict__ d_acc)             // (N,64)  -> workspace (zeroed)
{
    __shared__ float sW1[HID];
    __shared__ float sb1[HID];
    __shared__ float sb2[OUT2];
    __shared__ float sW2[HID * W2_PAD];

    const int tid = threadIdx.x;
    // cooperative weight staging
    for (int i = tid; i < HID; i += 256) { sW1[i] = W1[i]; sb1[i] = b1[i]; }
    for (int i = tid; i < OUT2; i += 256) { sb2[i] = b2[i]; }
    for (int i = tid; i < HID * OUT2; i += 256) {
        int r = i / OUT2, c = i - r * OUT2;
        sW2[r * W2_PAD + c] = W2[i];
    }
    __syncthreads();

    int e0 = blockIdx.x * 512 + tid;   // edge 0
    int e1 = e0 + 256;                 // edge 1

    float t0 = edge_attr[e0];
    float t1 = edge_attr[e1];

    float acc[2][OUT2];
#pragma unroll
    for (int k = 0; k < OUT2; ++k) { acc[0][k] = sb2[k]; acc[1][k] = sb2[k]; }

    // MLP: h_j = relu(t*W1[j]+b1[j]); acc[k] += h_j * W2[j][k]
#pragma unroll 2
    for (int j = 0; j < HID; ++j) {
        float h0 = fmaxf(fmaf(t0, sW1[j], sb1[j]), 0.0f);
        float h1 = fmaxf(fmaf(t1, sW1[j], sb1[j]), 0.0f);
        const float* wrow = &sW2[j * W2_PAD];
#pragma unroll
        for (int k = 0; k < OUT2; ++k) {
            float wv = wrow[k];
            acc[0][k] = fmaf(h0, wv, acc[0][k]);
            acc[1][k] = fmaf(h1, wv, acc[1][k]);
        }
    }

    // final relu (mlp_out)
#pragma unroll
    for (int k = 0; k < OUT2; ++k) {
        acc[0][k] = fmaxf(acc[0][k], 0.0f);
        acc[1][k] = fmaxf(acc[1][k], 0.0f);
    }

    const int   e[2] = { e0, e1 };
    const float t[2] = { t0, t1 };

#pragma unroll
    for (int g = 0; g < 2; ++g) {
        const int ee = e[g];
        const int s  = edge_index[ee];          // src row of (2,E)
        // bucket = clip((int)(dist/1.0), 0, 9)
        int bucket = (int)t[g];
        bucket = bucket < 0 ? 0 : (bucket > 9 ? 9 : bucket);

        // ---- store w row (16 x float4) ----
        float4* dst = (float4*)(wout + (long long)ee * COLS);
        // cols 0..9 one-hot, 10..63 = acc[g][0..53]
        {
            float c0 = (bucket == 0) ? 1.f : 0.f;
            float c1 = (bucket == 1) ? 1.f : 0.f;
            float c2 = (bucket == 2) ? 1.f : 0.f;
            float c3 = (bucket == 3) ? 1.f : 0.f;
            dst[0] = make_float4(c0, c1, c2, c3);
            float c4 = (bucket == 4) ? 1.f : 0.f;
            float c5 = (bucket == 5) ? 1.f : 0.f;
            float c6 = (bucket == 6) ? 1.f : 0.f;
            float c7 = (bucket == 7) ? 1.f : 0.f;
            dst[1] = make_float4(c4, c5, c6, c7);
            float c8 = (bucket == 8) ? 1.f : 0.f;
            float c9 = (bucket == 9) ? 1.f : 0.f;
            dst[2] = make_float4(c8, c9, acc[g][0], acc[g][1]);
        }
#pragma unroll
        for (int q = 3; q < 16; ++q) {
            int kbase = q * 4 - 10;
            dst[q] = make_float4(acc[g][kbase], acc[g][kbase + 1],
                                 acc[g][kbase + 2], acc[g][kbase + 3]);
        }

        // ---- atomic segment sum ----
        float* drow = d_acc + (long long)s * COLS;
        atomicAdd(&drow[bucket], 1.0f);
#pragma unroll
        for (int k = 0; k < OUT2; ++k) {
            float v = acc[g][k];
            if (v != 0.0f) atomicAdd(&drow[10 + k], v);
        }
    }
}

// ---------------- Pass 2: wtilde = (d!=0) ? w/d : 0, in place on d_out ----------------
// One thread per float4: E*16 = 25.6M threads = 100000 blocks * 256.
__global__ __launch_bounds__(256) void pass2_kernel(
    const int*   __restrict__ edge_index,
    const float* __restrict__ d_acc,
    float*       __restrict__ wbuf)
{
    unsigned idx = blockIdx.x * 256u + threadIdx.x;  // [0, E*16)
    unsigned e = idx >> 4;
    unsigned q = idx & 15u;
    int s = edge_index[e];

    float4 wv = ((const float4*)wbuf)[idx];
    const float4 dv = *(const float4*)(d_acc + (long long)s * COLS + q * 4);

    wv.x = (dv.x != 0.0f) ? wv.x * __builtin_amdgcn_rcpf(dv.x) : 0.0f;
    wv.y = (dv.y != 0.0f) ? wv.y * __builtin_amdgcn_rcpf(dv.y) : 0.0f;
    wv.z = (dv.z != 0.0f) ? wv.z * __builtin_amdgcn_rcpf(dv.z) : 0.0f;
    wv.w = (dv.w != 0.0f) ? wv.w * __builtin_amdgcn_rcpf(dv.w) : 0.0f;

    ((float4*)wbuf)[idx] = wv;
}

extern "C" void kernel_launch(void* const* d_in, const int* in_sizes, int n_in,
                              void* d_out, int out_size, void* d_ws, size_t ws_size,
                              hipStream_t stream) {
    // inputs: 0=x (unused), 1=edge_index, 2=edge_attr, 3=W1, 4=b1, 5=W2, 6=b2
    const int*   edge_index = (const int*)d_in[1];
    const float* edge_attr  = (const float*)d_in[2];
    const float* W1         = (const float*)d_in[3];
    const float* b1         = (const float*)d_in[4];
    const float* W2         = (const float*)d_in[5];
    const float* b2         = (const float*)d_in[6];
    float* out = (float*)d_out;
    float* d_acc = (float*)d_ws;   // N_NODES * 64 fp32 = 25.6 MB

    hipMemsetAsync(d_acc, 0, (size_t)N_NODES * COLS * sizeof(float), stream);

    pass1_kernel<<<N_EDGES / 512, 256, 0, stream>>>(
        edge_attr, edge_index, W1, b1, W2, b2, out, d_acc);

    pass2_kernel<<<(N_EDGES * 16) / 256, 256, 0, stream>>>(
        edge_index, d_acc, out);
}

// Round 2
// 1279.036 us; speedup vs baseline: 2.4206x; 2.4206x over previous
//
#include <hip/hip_runtime.h>

#define N_NODES   100000
#define N_EDGES   1600000
#define COLS      64      // 10 one-hot + 54 mlp
#define HID       128
#define OUT2      54
#define W2_PAD    56      // pad LDS rows to 16B alignment

// workspace layout (bytes)
#define OFF_DACC    0ull                       // N_NODES*64 fp32 = 25,600,000
#define OFF_COUNTS  25600000ull                // N_NODES int    =    400,000
#define OFF_CURSOR  26000000ull                // N_NODES int    =    400,000
#define OFF_SORTED  26400000ull                // N_EDGES int    =  6,400,000
                                               // total 32.8 MB

// ---------------- P1: compute w -> d_out, histogram src counts ----------------
// 256 threads, 512 edges/block (2 per thread). 3125 blocks.
__global__ __launch_bounds__(256) void pass1_kernel(
    const float* __restrict__ edge_attr,   // (E,1)
    const int*   __restrict__ edge_index,  // (2,E); row 0 = src
    const float* __restrict__ W1,
    const float* __restrict__ b1,
    const float* __restrict__ W2,
    const float* __restrict__ b2,
    float* __restrict__ wout,              // (E,64) -> d_out
    int*   __restrict__ counts)            // (N,)   zeroed
{
    __shared__ float sW1[HID];
    __shared__ float sb1[HID];
    __shared__ float sb2[OUT2];
    __shared__ float sW2[HID * W2_PAD];

    const int tid = threadIdx.x;
    for (int i = tid; i < HID; i += 256) { sW1[i] = W1[i]; sb1[i] = b1[i]; }
    for (int i = tid; i < OUT2; i += 256) { sb2[i] = b2[i]; }
    for (int i = tid; i < HID * OUT2; i += 256) {
        int r = i / OUT2, c = i - r * OUT2;
        sW2[r * W2_PAD + c] = W2[i];
    }
    __syncthreads();

    int e0 = blockIdx.x * 512 + tid;
    int e1 = e0 + 256;

    float t0 = edge_attr[e0];
    float t1 = edge_attr[e1];

    float acc[2][OUT2];
#pragma unroll
    for (int k = 0; k < OUT2; ++k) { acc[0][k] = sb2[k]; acc[1][k] = sb2[k]; }

#pragma unroll 2
    for (int j = 0; j < HID; ++j) {
        float h0 = fmaxf(fmaf(t0, sW1[j], sb1[j]), 0.0f);
        float h1 = fmaxf(fmaf(t1, sW1[j], sb1[j]), 0.0f);
        const float* wrow = &sW2[j * W2_PAD];
#pragma unroll
        for (int k = 0; k < OUT2; ++k) {
            float wv = wrow[k];
            acc[0][k] = fmaf(h0, wv, acc[0][k]);
            acc[1][k] = fmaf(h1, wv, acc[1][k]);
        }
    }

#pragma unroll
    for (int k = 0; k < OUT2; ++k) {
        acc[0][k] = fmaxf(acc[0][k], 0.0f);
        acc[1][k] = fmaxf(acc[1][k], 0.0f);
    }

    const int   e[2] = { e0, e1 };
    const float t[2] = { t0, t1 };

#pragma unroll
    for (int g = 0; g < 2; ++g) {
        const int ee = e[g];
        const int s  = edge_index[ee];
        int bucket = (int)t[g];
        bucket = bucket < 0 ? 0 : (bucket > 9 ? 9 : bucket);

        float4* dst = (float4*)(wout + (long long)ee * COLS);
        {
            float c0 = (bucket == 0) ? 1.f : 0.f;
            float c1 = (bucket == 1) ? 1.f : 0.f;
            float c2 = (bucket == 2) ? 1.f : 0.f;
            float c3 = (bucket == 3) ? 1.f : 0.f;
            dst[0] = make_float4(c0, c1, c2, c3);
            float c4 = (bucket == 4) ? 1.f : 0.f;
            float c5 = (bucket == 5) ? 1.f : 0.f;
            float c6 = (bucket == 6) ? 1.f : 0.f;
            float c7 = (bucket == 7) ? 1.f : 0.f;
            dst[1] = make_float4(c4, c5, c6, c7);
            float c8 = (bucket == 8) ? 1.f : 0.f;
            float c9 = (bucket == 9) ? 1.f : 0.f;
            dst[2] = make_float4(c8, c9, acc[g][0], acc[g][1]);
        }
#pragma unroll
        for (int q = 3; q < 16; ++q) {
            int kbase = q * 4 - 10;
            dst[q] = make_float4(acc[g][kbase], acc[g][kbase + 1],
                                 acc[g][kbase + 2], acc[g][kbase + 3]);
        }

        atomicAdd(&counts[s], 1);
    }
}

// ---------------- K2: exclusive scan of counts -> cursor (single block) -------
__global__ __launch_bounds__(1024) void scan_kernel(
    const int* __restrict__ counts, int* __restrict__ cursor)
{
    __shared__ int wsum[16];
    __shared__ int wbase[16];
    __shared__ int carry;
    const int tid  = threadIdx.x;
    const int lane = tid & 63;
    const int wid  = tid >> 6;
    if (tid == 0) carry = 0;
    __syncthreads();

    const int nchunk = (N_NODES + 1023) / 1024;   // 98
    for (int chunk = 0; chunk < nchunk; ++chunk) {
        int i = chunk * 1024 + tid;
        int v = (i < N_NODES) ? counts[i] : 0;
        // wave-inclusive scan
        int incl = v;
#pragma unroll
        for (int off = 1; off < 64; off <<= 1) {
            int u = __shfl_up(incl, off, 64);
            if (lane >= off) incl += u;
        }
        if (lane == 63) wsum[wid] = incl;
        __syncthreads();
        if (tid == 0) {
            int run = carry;
#pragma unroll
            for (int w = 0; w < 16; ++w) { int s = wsum[w]; wbase[w] = run; run += s; }
            carry = run;
        }
        __syncthreads();
        if (i < N_NODES) cursor[i] = incl - v + wbase[wid];
    }
}

// ---------------- K3: scatter edge ids sorted by src --------------------------
__global__ __launch_bounds__(256) void scatter_kernel(
    const int* __restrict__ edge_index,
    int* __restrict__ cursor,
    int* __restrict__ sorted_eid)
{
    int e = blockIdx.x * 256 + threadIdx.x;
    int s = edge_index[e];
    int pos = atomicAdd(&cursor[s], 1);
    sorted_eid[pos] = e;
}

// ---------------- K4: per-node segment sum of w rows -> d_acc -----------------
// one wave per node; 4 edges in flight (16 lanes x float4 each)
__global__ __launch_bounds__(256) void dsum_kernel(
    const float* __restrict__ wbuf,        // (E,64)
    const int*   __restrict__ counts,
    const int*   __restrict__ cursor,      // post-scatter: offset + count
    const int*   __restrict__ sorted_eid,
    float*       __restrict__ d_acc)       // (N,64)
{
    const int node = blockIdx.x * 4 + (threadIdx.x >> 6);
    const int lane = threadIdx.x & 63;
    const int c    = lane & 15;            // float4 slot within row
    const int g    = lane >> 4;            // edge slot 0..3

    const int n    = counts[node];
    const int base = cursor[node] - n;

    float4 acc = make_float4(0.f, 0.f, 0.f, 0.f);
    for (int i = 0; i < n; i += 4) {
        int idx = i + g;
        if (idx < n) {
            int eid = sorted_eid[base + idx];
            float4 wv = ((const float4*)(wbuf + (long long)eid * COLS))[c];
            acc.x += wv.x; acc.y += wv.y; acc.z += wv.z; acc.w += wv.w;
        }
    }
    // reduce across the 4 edge-slot groups (lanes differing in bits 4,5)
#pragma unroll
    for (int m = 16; m <= 32; m <<= 1) {
        acc.x += __shfl_xor(acc.x, m, 64);
        acc.y += __shfl_xor(acc.y, m, 64);
        acc.z += __shfl_xor(acc.z, m, 64);
        acc.w += __shfl_xor(acc.w, m, 64);
    }
    if (g == 0) {
        ((float4*)(d_acc + (long long)node * COLS))[c] = acc;
    }
}

// ---------------- P2: wtilde = (d!=0) ? w/d : 0, in place on d_out ------------
__global__ __launch_bounds__(256) void pass2_kernel(
    const int*   __restrict__ edge_index,
    const float* __restrict__ d_acc,
    float*       __restrict__ wbuf)
{
    unsigned idx = blockIdx.x * 256u + threadIdx.x;  // [0, E*16)
    unsigned e = idx >> 4;
    unsigned q = idx & 15u;
    int s = edge_index[e];

    float4 wv = ((const float4*)wbuf)[idx];
    const float4 dv = *(const float4*)(d_acc + (long long)s * COLS + q * 4);

    wv.x = (dv.x != 0.0f) ? wv.x * __builtin_amdgcn_rcpf(dv.x) : 0.0f;
    wv.y = (dv.y != 0.0f) ? wv.y * __builtin_amdgcn_rcpf(dv.y) : 0.0f;
    wv.z = (dv.z != 0.0f) ? wv.z * __builtin_amdgcn_rcpf(dv.z) : 0.0f;
    wv.w = (dv.w != 0.0f) ? wv.w * __builtin_amdgcn_rcpf(dv.w) : 0.0f;

    ((float4*)wbuf)[idx] = wv;
}

extern "C" void kernel_launch(void* const* d_in, const int* in_sizes, int n_in,
                              void* d_out, int out_size, void* d_ws, size_t ws_size,
                              hipStream_t stream) {
    // inputs: 0=x (unused), 1=edge_index, 2=edge_attr, 3=W1, 4=b1, 5=W2, 6=b2
    const int*   edge_index = (const int*)d_in[1];
    const float* edge_attr  = (const float*)d_in[2];
    const float* W1         = (const float*)d_in[3];
    const float* b1         = (const float*)d_in[4];
    const float* W2         = (const float*)d_in[5];
    const float* b2         = (const float*)d_in[6];
    float* out = (float*)d_out;

    char* ws = (char*)d_ws;
    float* d_acc      = (float*)(ws + OFF_DACC);
    int*   counts     = (int*)  (ws + OFF_COUNTS);
    int*   cursor     = (int*)  (ws + OFF_CURSOR);
    int*   sorted_eid = (int*)  (ws + OFF_SORTED);

    hipMemsetAsync(counts, 0, (size_t)N_NODES * sizeof(int), stream);

    pass1_kernel<<<N_EDGES / 512, 256, 0, stream>>>(
        edge_attr, edge_index, W1, b1, W2, b2, out, counts);

    scan_kernel<<<1, 1024, 0, stream>>>(counts, cursor);

    scatter_kernel<<<N_EDGES / 256, 256, 0, stream>>>(
        edge_index, cursor, sorted_eid);

    dsum_kernel<<<N_NODES / 4, 256, 0, stream>>>(
        out, counts, cursor, sorted_eid, d_acc);

    pass2_kernel<<<(N_EDGES * 16) / 256, 256, 0, stream>>>(
        edge_index, d_acc, out);
}